// Round 2
// baseline (315.089 us; speedup 1.0000x reference)
//
#include <hip/hip_runtime.h>

#define DD 1024
#define TD 62          // valid output columns per tile (64 LDS cols incl. 1 halo each side)
#define NTILE 17       // ceil(1024/62)
#define BB 256

typedef __attribute__((ext_vector_type(8))) short short8;
typedef __attribute__((ext_vector_type(4))) float float4_;

__device__ __forceinline__ unsigned short f2bf(float f) {
    union { float f; unsigned u; } v; v.f = f;
    unsigned u = v.u;
    return (unsigned short)((u + 0x7fffu + ((u >> 16) & 1u)) >> 16);  // RNE
}
__device__ __forceinline__ unsigned pack2(float a, float b) {
    return (unsigned)f2bf(a) | ((unsigned)f2bf(b) << 16);
}
// fp16 pair pack/unpack for L'/R' LDS storage (fp16: rel err 2^-11, negligible here)
__device__ __forceinline__ unsigned packh2(float a, float b) {
    union { _Float16 h[2]; unsigned u; } v;
    v.h[0] = (_Float16)a; v.h[1] = (_Float16)b;
    return v.u;
}
__device__ __forceinline__ float h2f_lo(unsigned u) {
    union { unsigned u; _Float16 h[2]; } v; v.u = u; return (float)v.h[0];
}
__device__ __forceinline__ float h2f_hi(unsigned u) {
    union { unsigned u; _Float16 h[2]; } v; v.u = u; return (float)v.h[1];
}

// ws (bf16 elements): [0,24576) conv A-frags  W2c[t][q][w][lane][j]
//                     [24576,32768) linear A-frags Wf[mat][l0s][mt][lane][j]
__global__ void prep_w(const float* __restrict__ Wconv,
                       const float* __restrict__ Wl,
                       const float* __restrict__ Wr,
                       unsigned short* __restrict__ W2) {
    int o = blockIdx.x * 256 + threadIdx.x;          // 0..32767
    if (o < 24576) {
        int j = o & 7, lane = (o >> 3) & 63, w = (o >> 9) & 3, q = (o >> 11) & 3, t = o >> 13;
        int m = lane & 15, quad = lane >> 4;
        int k = 16 * w + m, c = 32 * q + 8 * quad + j;
        W2[o] = f2bf(Wconv[(k * 128 + c) * 3 + t]);
    } else {
        int o2 = o - 24576;
        int j = o2 & 7, lane = (o2 >> 3) & 63, mt = (o2 >> 9) & 3,
            l0s = (o2 >> 11) & 1, mat = (o2 >> 12) & 1;
        int m = lane & 15, quad = lane >> 4;
        int k = 16 * mt + m, l = 32 * l0s + quad * 8 + j;
        const float* src = mat ? Wr : Wl;
        W2[o] = f2bf(src[k * 64 + l]);
    }
}

// merged corr: for ii in [0,16): i = 16W+ii
//   accA[ii] = corr[i]    = sum_{j=0..i}   L[j]*R[j+63-i]
//   accB[ii] = corr[i+64] = sum_{j=i+1..63} L[j]*R[j-1-i]
// L' is read from fp16-pair LDS (swizzled); R' column pre-unpacked into Rr[64].
template<int W>
__device__ __forceinline__ void corrAB(const unsigned* __restrict__ Lh, const float (&Rr)[64],
                                       float (&accA)[16], float (&accB)[16], int lane) {
#pragma unroll
    for (int ii = 0; ii < 16; ++ii) { accA[ii] = 0.0f; accB[ii] = 0.0f; }
#pragma unroll
    for (int j2 = 0; j2 < 32; ++j2) {
        unsigned u = Lh[j2 * 64 + (lane ^ (((j2 >> 1) & 1) << 4))];
        float Lj0 = h2f_lo(u), Lj1 = h2f_hi(u);
#pragma unroll
        for (int jj = 0; jj < 2; ++jj) {
            const int j = 2 * j2 + jj;
            const float Lj = jj ? Lj1 : Lj0;
#pragma unroll
            for (int ii = 0; ii < 16; ++ii) {
                const int i = 16 * W + ii;
                if (j <= i) accA[ii] += Lj * Rr[j + 63 - i];
                else        accB[ii] += Lj * Rr[j - 1 - i];
            }
        }
    }
}

template<bool PRE>
__global__ __launch_bounds__(256, 4)
void fused_cc_kernel(const float* __restrict__ left,
                     const float* __restrict__ right,
                     const float* __restrict__ Wl,
                     const float* __restrict__ bl,
                     const float* __restrict__ Wr,
                     const float* __restrict__ br,
                     const float* __restrict__ Wconv,
                     const unsigned short* __restrict__ W2,
                     float* __restrict__ out) {
    // 32 KiB total -> 4 blocks/CU.
    // shm[0..4095]    : staging xL[2048]+xR[2048]  |  later corrT bf16 [64][128] swizzled
    // shm[4096..6143] : Lh fp16-pairs [32 lpair][64 d] (quad-parity swizzle)
    // shm[6144..8191] : Rh fp16-pairs
    __shared__ unsigned shm[8192];
    unsigned* xL = shm;
    unsigned* xR = shm + 2048;
    unsigned* Lh = shm + 4096;
    unsigned* Rh = shm + 6144;
    unsigned short* corrT = (unsigned short*)shm;

    const int tid  = threadIdx.x;
    const int lane = tid & 63;
    const int w    = __builtin_amdgcn_readfirstlane(tid >> 6);
    const int kw   = 16 * w;
    const int m16  = lane & 15;
    const int quad = lane >> 4;

    const int b       = blockIdx.y;
    const int d_start = blockIdx.x * TD;
    const int ncols   = min(TD, DD - d_start);

    const int  g        = d_start - 1 + lane;      // global d for local column = lane
    const bool colvalid = (g >= 0) && (g < DD);

    const float* lb = left  + (size_t)b * 64 * DD;
    const float* rb = right + (size_t)b * 64 * DD;

    // ---- hoisted: linear A-frags + biases (global loads overlap P1's input loads)
    short8 afL[2], afR[2];
    if (PRE) {
        const short8* Wf = (const short8*)(W2 + 24576);
        afL[0] = Wf[(0 * 4 + w) * 64 + lane];      // [mat0][l0s0][mt=w]
        afL[1] = Wf[(1 * 4 + w) * 64 + lane];      // [mat0][l0s1]
        afR[0] = Wf[(2 * 4 + w) * 64 + lane];      // [mat1][l0s0]
        afR[1] = Wf[(3 * 4 + w) * 64 + lane];      // [mat1][l0s1]
    } else {
#pragma unroll
        for (int l0s = 0; l0s < 2; ++l0s) {
            const float* pL = Wl + (kw + m16) * 64 + 32 * l0s + quad * 8;
            const float* pR = Wr + (kw + m16) * 64 + 32 * l0s + quad * 8;
#pragma unroll
            for (int j = 0; j < 8; ++j) {
                afL[l0s][j] = (short)f2bf(pL[j]);
                afR[l0s][j] = (short)f2bf(pR[j]);
            }
        }
    }
    float blv[4], brv[4];
#pragma unroll
    for (int r = 0; r < 4; ++r) {
        int krow = kw + quad * 4 + r;
        blv[r] = bl[krow]; brv[r] = br[krow];
    }

    // ---- P1: stage both inputs as bf16 l-pairs (coalesced global; swizzled LDS dest)
#pragma unroll
    for (int i = 0; i < 8; ++i) {
        int p = 8 * w + i, l = 2 * p;
        float a0 = colvalid ? lb[l * DD + g] : 0.0f;
        float a1 = colvalid ? lb[(l + 1) * DD + g] : 0.0f;
        float c0 = colvalid ? rb[l * DD + g] : 0.0f;
        float c1 = colvalid ? rb[(l + 1) * DD + g] : 0.0f;
        int pc = lane ^ (((p >> 2) & 1) << 4);     // quad-parity swizzle (matches P2 reads)
        xL[p * 64 + pc] = pack2(a0, a1);
        xR[p * 64 + pc] = pack2(c0, c1);
    }
    __syncthreads();

    // ---- P2: both linears via MFMA (A = W frags, B = staged input), M=64,N=64,K=64
    float4_ accL[4], accR[4];
#pragma unroll
    for (int nt = 0; nt < 4; ++nt) { accL[nt] = (float4_){0,0,0,0}; accR[nt] = (float4_){0,0,0,0}; }
#pragma unroll
    for (int l0s = 0; l0s < 2; ++l0s)
#pragma unroll
        for (int nt = 0; nt < 4; ++nt) {
            union { unsigned u[4]; short8 s; } tL, tR;
#pragma unroll
            for (int jj = 0; jj < 4; ++jj) {
                int row = l0s * 16 + quad * 4 + jj;
                int col = (nt * 16 + m16) ^ (((row >> 2) & 1) << 4);
                int a = row * 64 + col;
                tL.u[jj] = xL[a];
                tR.u[jj] = xR[a];
            }
            accL[nt] = __builtin_amdgcn_mfma_f32_16x16x32_bf16(afL[l0s], tL.s, accL[nt], 0, 0, 0);
            accR[nt] = __builtin_amdgcn_mfma_f32_16x16x32_bf16(afR[l0s], tR.s, accR[nt], 0, 0, 0);
        }

    // bias + scatter C-layout -> Lh/Rh fp16 pairs [k2][d] (swizzled, conflict-free)
#pragma unroll
    for (int nt = 0; nt < 4; ++nt) {
        int col = nt * 16 + m16;
        int k2  = 8 * w + 2 * quad;               // pair rows (kw+4q)/2 and +1
        int c0 = col ^ ((quad & 1) << 4);         // ((k2>>1)&1) == quad&1 for both pairs
        Lh[k2 * 64 + c0]       = packh2(accL[nt][0] + blv[0], accL[nt][1] + blv[1]);
        Lh[(k2 + 1) * 64 + c0] = packh2(accL[nt][2] + blv[2], accL[nt][3] + blv[3]);
        Rh[k2 * 64 + c0]       = packh2(accR[nt][0] + brv[0], accR[nt][1] + brv[1]);
        Rh[(k2 + 1) * 64 + c0] = packh2(accR[nt][2] + brv[2], accR[nt][3] + brv[3]);
    }
    __syncthreads();   // staging reads done everywhere; Lh/Rh visible

    // ---- P3: merged, balanced corr (1024 FMAs/thread) -> corrT (bf16, swizzled)
    float Rr[64];
#pragma unroll
    for (int k2 = 0; k2 < 32; ++k2) {
        unsigned u = Rh[k2 * 64 + (lane ^ (((k2 >> 1) & 1) << 4))];
        Rr[2 * k2]     = h2f_lo(u);
        Rr[2 * k2 + 1] = h2f_hi(u);
    }

    float accA[16], accB[16];
    switch (w) {
        case 0: corrAB<0>(Lh, Rr, accA, accB, lane); break;
        case 1: corrAB<1>(Lh, Rr, accA, accB, lane); break;
        case 2: corrAB<2>(Lh, Rr, accA, accB, lane); break;
        default: corrAB<3>(Lh, Rr, accA, accB, lane); break;
    }

    // issue conv A-frag loads now: latency hides under corrT pack/write + barrier
    short8 af[12];
#pragma unroll
    for (int t = 0; t < 3; ++t)
#pragma unroll
        for (int qi = 0; qi < 4; ++qi) {
            if (PRE) {
                af[t * 4 + qi] = ((const short8*)W2)[((t * 4 + qi) * 4 + w) * 64 + lane];
            } else {
                const float* p = Wconv + ((kw + m16) * 128 + 32 * qi + 8 * quad) * 3 + t;
#pragma unroll
                for (int j = 0; j < 8; ++j) af[t * 4 + qi][j] = (short)f2bf(p[3 * j]);
            }
        }

    // write 4 swizzled b128 stores: cols [kw,kw+16) -> groups {2w,2w+1}; +64 -> {8+2w,8+2w+1}
    {
        const float* srcs[4] = { accA, accA + 8, accB, accB + 8 };
        const int grps[4] = { 2 * w, 2 * w + 1, 8 + 2 * w, 8 + 2 * w + 1 };
#pragma unroll
        for (int s = 0; s < 4; ++s) {
            short8 v;
#pragma unroll
            for (int j = 0; j < 8; ++j) v[j] = colvalid ? (short)f2bf(srcs[s][j]) : (short)0;
            int phys = grps[s] ^ (lane & 7);
            *(short8*)&corrT[lane * 128 + phys * 8] = v;
        }
    }
    __syncthreads();

    // ---- P4: conv via MFMA over all 128 c (3 taps x 4 c-groups x 4 n-tiles)
    // rows 64,65 (only feeding discarded output cols 62,63) read harmless garbage from Lh.
    float4_ yacc[4];
#pragma unroll
    for (int nt = 0; nt < 4; ++nt) yacc[nt] = (float4_){0,0,0,0};
#pragma unroll
    for (int t = 0; t < 3; ++t)
#pragma unroll
        for (int qi = 0; qi < 4; ++qi)
#pragma unroll
            for (int nt = 0; nt < 4; ++nt) {
                int row  = nt * 16 + m16 + t;                 // 0..65 (64,65 -> discarded cols)
                int phys = (4 * qi + quad) ^ (row & 7);
                short8 bf = *(const short8*)&corrT[row * 128 + phys * 8];
                yacc[nt] = __builtin_amdgcn_mfma_f32_16x16x32_bf16(af[t * 4 + qi], bf,
                                                                   yacc[nt], 0, 0, 0);
            }

    // ---- P5: store y[b,k,d]  (D layout: col=lane&15 -> d, row=quad*4+r -> k)
#pragma unroll
    for (int nt = 0; nt < 4; ++nt) {
        const int dd = nt * 16 + m16;
        if (dd < ncols) {
#pragma unroll
            for (int r = 0; r < 4; ++r) {
                int k = kw + 4 * quad + r;
                out[((size_t)b * 64 + k) * DD + d_start + dd] = yacc[nt][r];
            }
        }
    }
}

extern "C" void kernel_launch(void* const* d_in, const int* in_sizes, int n_in,
                              void* d_out, int out_size, void* d_ws, size_t ws_size,
                              hipStream_t stream) {
    const float* left  = (const float*)d_in[0];
    const float* right = (const float*)d_in[1];
    const float* Wl    = (const float*)d_in[2];
    const float* bl    = (const float*)d_in[3];
    const float* Wr    = (const float*)d_in[4];
    const float* br    = (const float*)d_in[5];
    const float* Wconv = (const float*)d_in[6];
    float* out = (float*)d_out;

    dim3 grid(NTILE, BB);
    if (ws_size >= 32768 * sizeof(unsigned short)) {
        unsigned short* W2 = (unsigned short*)d_ws;
        prep_w<<<128, 256, 0, stream>>>(Wconv, Wl, Wr, W2);
        fused_cc_kernel<true><<<grid, dim3(256), 0, stream>>>(left, right, Wl, bl, Wr, br,
                                                              Wconv, W2, out);
    } else {
        fused_cc_kernel<false><<<grid, dim3(256), 0, stream>>>(left, right, Wl, bl, Wr, br,
                                                               Wconv, nullptr, out);
    }
}

// Round 3
// 256.057 us; speedup vs baseline: 1.2305x; 1.2305x over previous
//
#include <hip/hip_runtime.h>

#define DD 1024
#define TD 62          // valid output columns per tile (64 LDS cols incl. 1 halo each side)
#define NTILE 17       // ceil(1024/62)
#define BB 256

typedef __attribute__((ext_vector_type(8))) short short8;
typedef __attribute__((ext_vector_type(4))) float float4_;

__device__ __forceinline__ unsigned short f2bf(float f) {
    union { float f; unsigned u; } v; v.f = f;
    unsigned u = v.u;
    return (unsigned short)((u + 0x7fffu + ((u >> 16) & 1u)) >> 16);  // RNE
}
__device__ __forceinline__ unsigned pack2(float a, float b) {
    return (unsigned)f2bf(a) | ((unsigned)f2bf(b) << 16);
}
// fp16 pair pack/unpack for L'/R' LDS storage (fp16: rel err 2^-11, negligible here)
__device__ __forceinline__ unsigned packh2(float a, float b) {
    union { _Float16 h[2]; unsigned u; } v;
    v.h[0] = (_Float16)a; v.h[1] = (_Float16)b;
    return v.u;
}
__device__ __forceinline__ float h2f_lo(unsigned u) {
    union { unsigned u; _Float16 h[2]; } v; v.u = u; return (float)v.h[0];
}
__device__ __forceinline__ float h2f_hi(unsigned u) {
    union { unsigned u; _Float16 h[2]; } v; v.u = u; return (float)v.h[1];
}

// ws (bf16 elements): [0,24576) conv A-frags  W2c[t][q][w][lane][j]
//                     [24576,32768) linear A-frags Wf[mat][l0s][mt][lane][j]
__global__ void prep_w(const float* __restrict__ Wconv,
                       const float* __restrict__ Wl,
                       const float* __restrict__ Wr,
                       unsigned short* __restrict__ W2) {
    int o = blockIdx.x * 256 + threadIdx.x;          // 0..32767
    if (o < 24576) {
        int j = o & 7, lane = (o >> 3) & 63, w = (o >> 9) & 3, q = (o >> 11) & 3, t = o >> 13;
        int m = lane & 15, quad = lane >> 4;
        int k = 16 * w + m, c = 32 * q + 8 * quad + j;
        W2[o] = f2bf(Wconv[(k * 128 + c) * 3 + t]);
    } else {
        int o2 = o - 24576;
        int j = o2 & 7, lane = (o2 >> 3) & 63, mt = (o2 >> 9) & 3,
            l0s = (o2 >> 11) & 1, mat = (o2 >> 12) & 1;
        int m = lane & 15, quad = lane >> 4;
        int k = 16 * mt + m, l = 32 * l0s + quad * 8 + j;
        const float* src = mat ? Wr : Wl;
        W2[o] = f2bf(src[k * 64 + l]);
    }
}

// merged corr: for ii in [0,16): i = 16W+ii
//   accA[ii] = corr[i]    = sum_{j=0..i}   L[j]*R[j+63-i]
//   accB[ii] = corr[i+64] = sum_{j=i+1..63} L[j]*R[j-1-i]
// L' is read from fp16-pair LDS (swizzled); R' column pre-unpacked into Rr[64].
template<int W>
__device__ __forceinline__ void corrAB(const unsigned* __restrict__ Lh, const float (&Rr)[64],
                                       float (&accA)[16], float (&accB)[16], int lane) {
#pragma unroll
    for (int ii = 0; ii < 16; ++ii) { accA[ii] = 0.0f; accB[ii] = 0.0f; }
#pragma unroll
    for (int j2 = 0; j2 < 32; ++j2) {
        unsigned u = Lh[j2 * 64 + (lane ^ (((j2 >> 1) & 1) << 4))];
        float Lj0 = h2f_lo(u), Lj1 = h2f_hi(u);
#pragma unroll
        for (int jj = 0; jj < 2; ++jj) {
            const int j = 2 * j2 + jj;
            const float Lj = jj ? Lj1 : Lj0;
#pragma unroll
            for (int ii = 0; ii < 16; ++ii) {
                const int i = 16 * W + ii;
                if (j <= i) accA[ii] += Lj * Rr[j + 63 - i];
                else        accB[ii] += Lj * Rr[j - 1 - i];
            }
        }
    }
}

template<bool PRE>
__global__ __launch_bounds__(256, 3)
void fused_cc_kernel(const float* __restrict__ left,
                     const float* __restrict__ right,
                     const float* __restrict__ Wl,
                     const float* __restrict__ bl,
                     const float* __restrict__ Wr,
                     const float* __restrict__ br,
                     const float* __restrict__ Wconv,
                     const unsigned short* __restrict__ W2,
                     float* __restrict__ out) {
    // 32 KiB total -> LDS allows 5 blocks/CU; VGPR (~84 @ min-3-waves) allows 6.
    // NOTE: launch_bounds min=4 made the allocator clamp to the 64-VGPR (8-wave)
    // boundary and spill ~190 B/thread to scratch (R1: WRITE_SIZE 327 MB). Keep 3.
    // shm[0..4095]    : staging xL[2048]+xR[2048]  |  later corrT bf16 [64][128] swizzled
    // shm[4096..6143] : Lh fp16-pairs [32 lpair][64 d] (quad-parity swizzle)
    // shm[6144..8191] : Rh fp16-pairs
    __shared__ unsigned shm[8192];
    unsigned* xL = shm;
    unsigned* xR = shm + 2048;
    unsigned* Lh = shm + 4096;
    unsigned* Rh = shm + 6144;
    unsigned short* corrT = (unsigned short*)shm;

    const int tid  = threadIdx.x;
    const int lane = tid & 63;
    const int w    = __builtin_amdgcn_readfirstlane(tid >> 6);
    const int kw   = 16 * w;
    const int m16  = lane & 15;
    const int quad = lane >> 4;

    const int b       = blockIdx.y;
    const int d_start = blockIdx.x * TD;
    const int ncols   = min(TD, DD - d_start);

    const int  g        = d_start - 1 + lane;      // global d for local column = lane
    const bool colvalid = (g >= 0) && (g < DD);

    const float* lb = left  + (size_t)b * 64 * DD;
    const float* rb = right + (size_t)b * 64 * DD;

    // ---- hoisted: linear A-frags + biases (global loads overlap P1's input loads)
    short8 afL[2], afR[2];
    if (PRE) {
        const short8* Wf = (const short8*)(W2 + 24576);
        afL[0] = Wf[(0 * 4 + w) * 64 + lane];      // [mat0][l0s0][mt=w]
        afL[1] = Wf[(1 * 4 + w) * 64 + lane];      // [mat0][l0s1]
        afR[0] = Wf[(2 * 4 + w) * 64 + lane];      // [mat1][l0s0]
        afR[1] = Wf[(3 * 4 + w) * 64 + lane];      // [mat1][l0s1]
    } else {
#pragma unroll
        for (int l0s = 0; l0s < 2; ++l0s) {
            const float* pL = Wl + (kw + m16) * 64 + 32 * l0s + quad * 8;
            const float* pR = Wr + (kw + m16) * 64 + 32 * l0s + quad * 8;
#pragma unroll
            for (int j = 0; j < 8; ++j) {
                afL[l0s][j] = (short)f2bf(pL[j]);
                afR[l0s][j] = (short)f2bf(pR[j]);
            }
        }
    }
    float blv[4], brv[4];
#pragma unroll
    for (int r = 0; r < 4; ++r) {
        int krow = kw + quad * 4 + r;
        blv[r] = bl[krow]; brv[r] = br[krow];
    }

    // ---- P1: stage both inputs as bf16 l-pairs (coalesced global; swizzled LDS dest)
#pragma unroll
    for (int i = 0; i < 8; ++i) {
        int p = 8 * w + i, l = 2 * p;
        float a0 = colvalid ? lb[l * DD + g] : 0.0f;
        float a1 = colvalid ? lb[(l + 1) * DD + g] : 0.0f;
        float c0 = colvalid ? rb[l * DD + g] : 0.0f;
        float c1 = colvalid ? rb[(l + 1) * DD + g] : 0.0f;
        int pc = lane ^ (((p >> 2) & 1) << 4);     // quad-parity swizzle (matches P2 reads)
        xL[p * 64 + pc] = pack2(a0, a1);
        xR[p * 64 + pc] = pack2(c0, c1);
    }
    __syncthreads();

    // ---- P2: both linears via MFMA (A = W frags, B = staged input), M=64,N=64,K=64
    float4_ accL[4], accR[4];
#pragma unroll
    for (int nt = 0; nt < 4; ++nt) { accL[nt] = (float4_){0,0,0,0}; accR[nt] = (float4_){0,0,0,0}; }
#pragma unroll
    for (int l0s = 0; l0s < 2; ++l0s)
#pragma unroll
        for (int nt = 0; nt < 4; ++nt) {
            union { unsigned u[4]; short8 s; } tL, tR;
#pragma unroll
            for (int jj = 0; jj < 4; ++jj) {
                int row = l0s * 16 + quad * 4 + jj;
                int col = (nt * 16 + m16) ^ (((row >> 2) & 1) << 4);
                int a = row * 64 + col;
                tL.u[jj] = xL[a];
                tR.u[jj] = xR[a];
            }
            accL[nt] = __builtin_amdgcn_mfma_f32_16x16x32_bf16(afL[l0s], tL.s, accL[nt], 0, 0, 0);
            accR[nt] = __builtin_amdgcn_mfma_f32_16x16x32_bf16(afR[l0s], tR.s, accR[nt], 0, 0, 0);
        }

    // bias + scatter C-layout -> Lh/Rh fp16 pairs [k2][d] (swizzled, conflict-free)
#pragma unroll
    for (int nt = 0; nt < 4; ++nt) {
        int col = nt * 16 + m16;
        int k2  = 8 * w + 2 * quad;               // pair rows (kw+4q)/2 and +1
        int c0 = col ^ ((quad & 1) << 4);         // ((k2>>1)&1) == quad&1 for both pairs
        Lh[k2 * 64 + c0]       = packh2(accL[nt][0] + blv[0], accL[nt][1] + blv[1]);
        Lh[(k2 + 1) * 64 + c0] = packh2(accL[nt][2] + blv[2], accL[nt][3] + blv[3]);
        Rh[k2 * 64 + c0]       = packh2(accR[nt][0] + brv[0], accR[nt][1] + brv[1]);
        Rh[(k2 + 1) * 64 + c0] = packh2(accR[nt][2] + brv[2], accR[nt][3] + brv[3]);
    }
    __syncthreads();   // staging reads done everywhere; Lh/Rh visible

    // ---- P3: merged, balanced corr (1024 FMAs/thread) -> corrT (bf16, swizzled)
    float Rr[64];
#pragma unroll
    for (int k2 = 0; k2 < 32; ++k2) {
        unsigned u = Rh[k2 * 64 + (lane ^ (((k2 >> 1) & 1) << 4))];
        Rr[2 * k2]     = h2f_lo(u);
        Rr[2 * k2 + 1] = h2f_hi(u);
    }

    float accA[16], accB[16];
    switch (w) {
        case 0: corrAB<0>(Lh, Rr, accA, accB, lane); break;
        case 1: corrAB<1>(Lh, Rr, accA, accB, lane); break;
        case 2: corrAB<2>(Lh, Rr, accA, accB, lane); break;
        default: corrAB<3>(Lh, Rr, accA, accB, lane); break;
    }

    // issue conv A-frag loads now: latency hides under corrT pack/write + barrier
    short8 af[12];
#pragma unroll
    for (int t = 0; t < 3; ++t)
#pragma unroll
        for (int qi = 0; qi < 4; ++qi) {
            if (PRE) {
                af[t * 4 + qi] = ((const short8*)W2)[((t * 4 + qi) * 4 + w) * 64 + lane];
            } else {
                const float* p = Wconv + ((kw + m16) * 128 + 32 * qi + 8 * quad) * 3 + t;
#pragma unroll
                for (int j = 0; j < 8; ++j) af[t * 4 + qi][j] = (short)f2bf(p[3 * j]);
            }
        }

    // write 4 swizzled b128 stores: cols [kw,kw+16) -> groups {2w,2w+1}; +64 -> {8+2w,8+2w+1}
    {
        const float* srcs[4] = { accA, accA + 8, accB, accB + 8 };
        const int grps[4] = { 2 * w, 2 * w + 1, 8 + 2 * w, 8 + 2 * w + 1 };
#pragma unroll
        for (int s = 0; s < 4; ++s) {
            short8 v;
#pragma unroll
            for (int j = 0; j < 8; ++j) v[j] = colvalid ? (short)f2bf(srcs[s][j]) : (short)0;
            int phys = grps[s] ^ (lane & 7);
            *(short8*)&corrT[lane * 128 + phys * 8] = v;
        }
    }
    __syncthreads();

    // ---- P4: conv via MFMA over all 128 c (3 taps x 4 c-groups x 4 n-tiles)
    // rows 64,65 (only feeding discarded output cols 62,63) read harmless garbage from Lh.
    float4_ yacc[4];
#pragma unroll
    for (int nt = 0; nt < 4; ++nt) yacc[nt] = (float4_){0,0,0,0};
#pragma unroll
    for (int t = 0; t < 3; ++t)
#pragma unroll
        for (int qi = 0; qi < 4; ++qi)
#pragma unroll
            for (int nt = 0; nt < 4; ++nt) {
                int row  = nt * 16 + m16 + t;                 // 0..65 (64,65 -> discarded cols)
                int phys = (4 * qi + quad) ^ (row & 7);
                short8 bf = *(const short8*)&corrT[row * 128 + phys * 8];
                yacc[nt] = __builtin_amdgcn_mfma_f32_16x16x32_bf16(af[t * 4 + qi], bf,
                                                                   yacc[nt], 0, 0, 0);
            }

    // ---- P5: store y[b,k,d]  (D layout: col=lane&15 -> d, row=quad*4+r -> k)
#pragma unroll
    for (int nt = 0; nt < 4; ++nt) {
        const int dd = nt * 16 + m16;
        if (dd < ncols) {
#pragma unroll
            for (int r = 0; r < 4; ++r) {
                int k = kw + 4 * quad + r;
                out[((size_t)b * 64 + k) * DD + d_start + dd] = yacc[nt][r];
            }
        }
    }
}

extern "C" void kernel_launch(void* const* d_in, const int* in_sizes, int n_in,
                              void* d_out, int out_size, void* d_ws, size_t ws_size,
                              hipStream_t stream) {
    const float* left  = (const float*)d_in[0];
    const float* right = (const float*)d_in[1];
    const float* Wl    = (const float*)d_in[2];
    const float* bl    = (const float*)d_in[3];
    const float* Wr    = (const float*)d_in[4];
    const float* br    = (const float*)d_in[5];
    const float* Wconv = (const float*)d_in[6];
    float* out = (float*)d_out;

    dim3 grid(NTILE, BB);
    if (ws_size >= 32768 * sizeof(unsigned short)) {
        unsigned short* W2 = (unsigned short*)d_ws;
        prep_w<<<128, 256, 0, stream>>>(Wconv, Wl, Wr, W2);
        fused_cc_kernel<true><<<grid, dim3(256), 0, stream>>>(left, right, Wl, bl, Wr, br,
                                                              Wconv, W2, out);
    } else {
        fused_cc_kernel<false><<<grid, dim3(256), 0, stream>>>(left, right, Wl, bl, Wr, br,
                                                               Wconv, nullptr, out);
    }
}

// Round 5
// 226.529 us; speedup vs baseline: 1.3909x; 1.1303x over previous
//
#include <hip/hip_runtime.h>

#define DD 1024
#define TD 62          // valid output columns per tile (64 LDS cols incl. 1 halo each side)
#define NTILE 17       // ceil(1024/62)
#define BB 256

typedef __attribute__((ext_vector_type(8))) short short8;
typedef __attribute__((ext_vector_type(4))) float float4_;
typedef _Float16 half2_ __attribute__((ext_vector_type(2)));

__device__ __forceinline__ unsigned short f2bf(float f) {
    union { float f; unsigned u; } v; v.f = f;
    unsigned u = v.u;
    return (unsigned short)((u + 0x7fffu + ((u >> 16) & 1u)) >> 16);  // RNE
}
__device__ __forceinline__ unsigned pack2(float a, float b) {
    return (unsigned)f2bf(a) | ((unsigned)f2bf(b) << 16);
}
// fp16 pair pack for L'/R' LDS storage (fp16: rel err 2^-11, negligible here)
__device__ __forceinline__ unsigned packh2(float a, float b) {
    union { _Float16 h[2]; unsigned u; } v;
    v.h[0] = (_Float16)a; v.h[1] = (_Float16)b;
    return v.u;
}
// v_dot2_f32_f16: 2 fp16 products accumulated into fp32 (same accuracy as unpack+2 fma)
__device__ __forceinline__ float fdot2f(unsigned a, unsigned b, float c) {
#if __has_builtin(__builtin_amdgcn_fdot2)
    union { unsigned u; half2_ h; } ua, ub; ua.u = a; ub.u = b;
    return __builtin_amdgcn_fdot2(ua.h, ub.h, c, false);
#else
    union { unsigned u; _Float16 h[2]; } ua, ub; ua.u = a; ub.u = b;
    return c + (float)ua.h[0] * (float)ub.h[0] + (float)ua.h[1] * (float)ub.h[1];
#endif
}

// ws (bf16 elements): [0,24576) conv A-frags  W2c[t][q][w][lane][j]
//                     [24576,32768) linear A-frags Wf[mat][l0s][mt][lane][j]
__global__ void prep_w(const float* __restrict__ Wconv,
                       const float* __restrict__ Wl,
                       const float* __restrict__ Wr,
                       unsigned short* __restrict__ W2) {
    int o = blockIdx.x * 256 + threadIdx.x;          // 0..32767
    if (o < 24576) {
        int j = o & 7, lane = (o >> 3) & 63, w = (o >> 9) & 3, q = (o >> 11) & 3, t = o >> 13;
        int m = lane & 15, quad = lane >> 4;
        int k = 16 * w + m, c = 32 * q + 8 * quad + j;
        W2[o] = f2bf(Wconv[(k * 128 + c) * 3 + t]);
    } else {
        int o2 = o - 24576;
        int j = o2 & 7, lane = (o2 >> 3) & 63, mt = (o2 >> 9) & 3,
            l0s = (o2 >> 11) & 1, mat = (o2 >> 12) & 1;
        int m = lane & 15, quad = lane >> 4;
        int k = 16 * mt + m, l = 32 * l0s + quad * 8 + j;
        const float* src = mat ? Wr : Wl;
        W2[o] = f2bf(src[k * 64 + l]);
    }
}

// ---- unified correlation pass (ONE code path shared by all 4 waves; I$-small) ----
// Cross-correlation view: corr[63-s] = F(L,R,s) = sum_j L[j]*R[j+s]  (s in [0,63])
//                         corr[64+s'] = F(R,L,s'+1)                  (s' in [0,63])
// Wave w runs 4 passes; each pass computes 8 shifts (one 8-channel corrT group):
//   A0: F(L,R, 8w+u)       -> group 7-w   A1: F(L,R, 56-8w+u) -> group w
//   B0: F(R,L, 8w+1+u)     -> group 8+w   B1: F(R,L, 57-8w+u) -> group 15-w
// shift s = 2q + ODD + u, with q = 4w or 28-4w (q%4==0 so the LDS pair-swizzle
// bit for Y pair t2+q equals ((t2>>1)&1), a compile-time immediate).
// P[t2] = Y-pair(t2+q), zeroed when t2+q>=32 (exact zero-padding of Y).
// AL[t2] = misaligned pair (hi of P[t2], lo of P[t2+1]).
// NOTE: swizzle is lane ^ (bit<<4), NOT lane + bit*16 (R4's bug).
template<int NJ2, bool ODD, bool REV>
__device__ __forceinline__ void corr_pass(const unsigned* __restrict__ X,
                                          const unsigned* __restrict__ Y,
                                          int q, int climit, int G,
                                          int lane, bool colvalid,
                                          unsigned short* __restrict__ corrT) {
    constexpr int SAFE = (NJ2 == 32) ? 20 : 4;   // t2 below SAFE can never have t2+q>=32
    unsigned P[NJ2 + 1];
    const unsigned* Yq = Y + q * 64;
#pragma unroll
    for (int t2 = 0; t2 <= NJ2; ++t2) {
        unsigned v = Yq[t2 * 64 + (lane ^ ((((t2 >> 1) & 1)) << 4))];
        if (t2 >= SAFE) { if (t2 + q >= 32) v = 0u; }
        P[t2] = v;
    }
    unsigned AL[NJ2];
#pragma unroll
    for (int t2 = 0; t2 < NJ2; ++t2)
        AL[t2] = (P[t2] >> 16) | (P[t2 + 1] << 16);   // v_alignbit

    float acc[8];
#pragma unroll
    for (int u = 0; u < 8; ++u) acc[u] = 0.0f;

#pragma unroll
    for (int c = 0; c < NJ2 / 4; ++c) {
        if (c < climit) {            // uniform early-skip; skipped chunks are all-zero terms
            unsigned xp[4];
#pragma unroll
            for (int jj = 0; jj < 4; ++jj) {
                int j2 = 4 * c + jj;
                xp[jj] = X[j2 * 64 + (lane ^ ((((j2 >> 1) & 1)) << 4))];
            }
#pragma unroll
            for (int jj = 0; jj < 4; ++jj) {
                int j2 = 4 * c + jj;
#pragma unroll
                for (int u = 0; u < 8; ++u) {
                    if (j2 < NJ2 - (u >> 1)) {
                        unsigned yv;
                        if (!ODD) yv = (u & 1) ? AL[j2 + (u >> 1)] : P[j2 + (u >> 1)];
                        else      yv = (u & 1) ? P[j2 + (u >> 1) + 1] : AL[j2 + (u >> 1)];
                        acc[u] = fdot2f(xp[jj], yv, acc[u]);
                    }
                }
            }
        }
    }
    // pack + swizzled b128 store of one 8-channel group
    short8 v;
#pragma unroll
    for (int u = 0; u < 8; ++u) {
        int jg = REV ? (7 - u) : u;
        v[jg] = colvalid ? (short)f2bf(acc[u]) : (short)0;   // colvalid = conv zero-pad at d=-1/D
    }
    int phys = G ^ (lane & 7);
    *(short8*)&corrT[lane * 128 + phys * 8] = v;
}

template<bool PRE>
__global__ __launch_bounds__(256, 3)
void fused_cc_kernel(const float* __restrict__ left,
                     const float* __restrict__ right,
                     const float* __restrict__ Wl,
                     const float* __restrict__ bl,
                     const float* __restrict__ Wr,
                     const float* __restrict__ br,
                     const float* __restrict__ Wconv,
                     const unsigned short* __restrict__ W2,
                     float* __restrict__ out) {
    // shm[0..4095]    : staging xL[2048]+xR[2048]  |  later corrT bf16 [64][128] swizzled
    // shm[4096..6143] : Lh fp16-pairs [32 lpair][64 d] (pair-parity swizzle)
    // shm[6144..8191] : Rh fp16-pairs
    // shm[8192..9087] : pad for corr_pass shifted Y-bank over-reads (values cndmask'd to 0)
    __shared__ unsigned shm[9088];
    unsigned* xL = shm;
    unsigned* xR = shm + 2048;
    unsigned* Lh = shm + 4096;
    unsigned* Rh = shm + 6144;
    unsigned short* corrT = (unsigned short*)shm;

    const int tid  = threadIdx.x;
    const int lane = tid & 63;
    const int w    = __builtin_amdgcn_readfirstlane(tid >> 6);
    const int kw   = 16 * w;
    const int m16  = lane & 15;
    const int quad = lane >> 4;

    const int b       = blockIdx.y;
    const int d_start = blockIdx.x * TD;
    const int ncols   = min(TD, DD - d_start);

    const int  g        = d_start - 1 + lane;      // global d for local column = lane
    const bool colvalid = (g >= 0) && (g < DD);

    const float* lb = left  + (size_t)b * 64 * DD;
    const float* rb = right + (size_t)b * 64 * DD;

    // ---- hoisted: linear A-frags + biases (global loads overlap P1's input loads)
    short8 afL[2], afR[2];
    if (PRE) {
        const short8* Wf = (const short8*)(W2 + 24576);
        afL[0] = Wf[(0 * 4 + w) * 64 + lane];
        afL[1] = Wf[(1 * 4 + w) * 64 + lane];
        afR[0] = Wf[(2 * 4 + w) * 64 + lane];
        afR[1] = Wf[(3 * 4 + w) * 64 + lane];
    } else {
#pragma unroll
        for (int l0s = 0; l0s < 2; ++l0s) {
            const float* pL = Wl + (kw + m16) * 64 + 32 * l0s + quad * 8;
            const float* pR = Wr + (kw + m16) * 64 + 32 * l0s + quad * 8;
#pragma unroll
            for (int j = 0; j < 8; ++j) {
                afL[l0s][j] = (short)f2bf(pL[j]);
                afR[l0s][j] = (short)f2bf(pR[j]);
            }
        }
    }
    float blv[4], brv[4];
#pragma unroll
    for (int r = 0; r < 4; ++r) {
        int krow = kw + quad * 4 + r;
        blv[r] = bl[krow]; brv[r] = br[krow];
    }

    // ---- P1: stage both inputs as bf16 l-pairs (coalesced global; swizzled LDS dest)
#pragma unroll
    for (int i = 0; i < 8; ++i) {
        int p = 8 * w + i, l = 2 * p;
        float a0 = colvalid ? lb[l * DD + g] : 0.0f;
        float a1 = colvalid ? lb[(l + 1) * DD + g] : 0.0f;
        float c0 = colvalid ? rb[l * DD + g] : 0.0f;
        float c1 = colvalid ? rb[(l + 1) * DD + g] : 0.0f;
        int pc = lane ^ (((p >> 2) & 1) << 4);     // quad-parity swizzle (matches P2 reads)
        xL[p * 64 + pc] = pack2(a0, a1);
        xR[p * 64 + pc] = pack2(c0, c1);
    }
    __syncthreads();

    // ---- P2: both linears via MFMA (A = W frags, B = staged input), M=64,N=64,K=64
    float4_ accL[4], accR[4];
#pragma unroll
    for (int nt = 0; nt < 4; ++nt) { accL[nt] = (float4_){0,0,0,0}; accR[nt] = (float4_){0,0,0,0}; }
#pragma unroll
    for (int l0s = 0; l0s < 2; ++l0s)
#pragma unroll
        for (int nt = 0; nt < 4; ++nt) {
            union { unsigned u[4]; short8 s; } tL, tR;
#pragma unroll
            for (int jj = 0; jj < 4; ++jj) {
                int row = l0s * 16 + quad * 4 + jj;
                int col = (nt * 16 + m16) ^ (((row >> 2) & 1) << 4);
                int a = row * 64 + col;
                tL.u[jj] = xL[a];
                tR.u[jj] = xR[a];
            }
            accL[nt] = __builtin_amdgcn_mfma_f32_16x16x32_bf16(afL[l0s], tL.s, accL[nt], 0, 0, 0);
            accR[nt] = __builtin_amdgcn_mfma_f32_16x16x32_bf16(afR[l0s], tR.s, accR[nt], 0, 0, 0);
        }

    // bias + scatter C-layout -> Lh/Rh fp16 pairs [k2][d] (pair-parity swizzle, conflict-free)
#pragma unroll
    for (int nt = 0; nt < 4; ++nt) {
        int col = nt * 16 + m16;
        int k2  = 8 * w + 2 * quad;               // pair rows (kw+4q)/2 and +1
        int c0 = col ^ ((quad & 1) << 4);         // ((k2>>1)&1) == quad&1 for both pairs
        Lh[k2 * 64 + c0]       = packh2(accL[nt][0] + blv[0], accL[nt][1] + blv[1]);
        Lh[(k2 + 1) * 64 + c0] = packh2(accL[nt][2] + blv[2], accL[nt][3] + blv[3]);
        Rh[k2 * 64 + c0]       = packh2(accR[nt][0] + brv[0], accR[nt][1] + brv[1]);
        Rh[(k2 + 1) * 64 + c0] = packh2(accR[nt][2] + brv[2], accR[nt][3] + brv[3]);
    }
    __syncthreads();   // staging reads done everywhere; Lh/Rh visible

    // ---- P3: unified balanced corr (shared code, dot2) -> corrT (bf16, swizzled)
    corr_pass<32, false, true >(Lh, Rh, 4 * w,      8 - w, 7 - w,  lane, colvalid, corrT);
    corr_pass<16, false, true >(Lh, Rh, 28 - 4 * w, w + 1, w,      lane, colvalid, corrT);
    corr_pass<32, true,  false>(Rh, Lh, 4 * w,      8 - w, 8 + w,  lane, colvalid, corrT);
    corr_pass<16, true,  false>(Rh, Lh, 28 - 4 * w, w + 1, 15 - w, lane, colvalid, corrT);

    // conv A-frag loads: latency hides under last stores + barrier
    short8 af[12];
#pragma unroll
    for (int t = 0; t < 3; ++t)
#pragma unroll
        for (int qi = 0; qi < 4; ++qi) {
            if (PRE) {
                af[t * 4 + qi] = ((const short8*)W2)[((t * 4 + qi) * 4 + w) * 64 + lane];
            } else {
                const float* p = Wconv + ((kw + m16) * 128 + 32 * qi + 8 * quad) * 3 + t;
#pragma unroll
                for (int j = 0; j < 8; ++j) af[t * 4 + qi][j] = (short)f2bf(p[3 * j]);
            }
        }
    __syncthreads();

    // ---- P4: conv via MFMA over all 128 c (3 taps x 4 c-groups x 4 n-tiles)
    // rows 64,65 (only feeding discarded output cols 62,63) read harmless garbage from Lh.
    float4_ yacc[4];
#pragma unroll
    for (int nt = 0; nt < 4; ++nt) yacc[nt] = (float4_){0,0,0,0};
#pragma unroll
    for (int t = 0; t < 3; ++t)
#pragma unroll
        for (int qi = 0; qi < 4; ++qi)
#pragma unroll
            for (int nt = 0; nt < 4; ++nt) {
                int row  = nt * 16 + m16 + t;                 // 0..65 (64,65 -> discarded cols)
                int phys = (4 * qi + quad) ^ (row & 7);
                short8 bf = *(const short8*)&corrT[row * 128 + phys * 8];
                yacc[nt] = __builtin_amdgcn_mfma_f32_16x16x32_bf16(af[t * 4 + qi], bf,
                                                                   yacc[nt], 0, 0, 0);
            }

    // ---- P5: store y[b,k,d]  (D layout: col=lane&15 -> d, row=quad*4+r -> k)
#pragma unroll
    for (int nt = 0; nt < 4; ++nt) {
        const int dd = nt * 16 + m16;
        if (dd < ncols) {
#pragma unroll
            for (int r = 0; r < 4; ++r) {
                int k = kw + 4 * quad + r;
                out[((size_t)b * 64 + k) * DD + d_start + dd] = yacc[nt][r];
            }
        }
    }
}

extern "C" void kernel_launch(void* const* d_in, const int* in_sizes, int n_in,
                              void* d_out, int out_size, void* d_ws, size_t ws_size,
                              hipStream_t stream) {
    const float* left  = (const float*)d_in[0];
    const float* right = (const float*)d_in[1];
    const float* Wl    = (const float*)d_in[2];
    const float* bl    = (const float*)d_in[3];
    const float* Wr    = (const float*)d_in[4];
    const float* br    = (const float*)d_in[5];
    const float* Wconv = (const float*)d_in[6];
    float* out = (float*)d_out;

    dim3 grid(NTILE, BB);
    if (ws_size >= 32768 * sizeof(unsigned short)) {
        unsigned short* W2 = (unsigned short*)d_ws;
        prep_w<<<128, 256, 0, stream>>>(Wconv, Wl, Wr, W2);
        fused_cc_kernel<true><<<grid, dim3(256), 0, stream>>>(left, right, Wl, bl, Wr, br,
                                                              Wconv, W2, out);
    } else {
        fused_cc_kernel<false><<<grid, dim3(256), 0, stream>>>(left, right, Wl, bl, Wr, br,
                                                               Wconv, nullptr, out);
    }
}

// Round 7
// 224.438 us; speedup vs baseline: 1.4039x; 1.0093x over previous
//
#include <hip/hip_runtime.h>

#define DD 1024
#define TD 62          // valid output columns per tile (64 LDS cols incl. 1 halo each side)
#define NTILE 17       // ceil(1024/62)
#define BB 256

typedef __attribute__((ext_vector_type(8))) short short8;
typedef __attribute__((ext_vector_type(4))) float float4_;
typedef _Float16 half2_ __attribute__((ext_vector_type(2)));

__device__ __forceinline__ unsigned short f2bf(float f) {
    union { float f; unsigned u; } v; v.f = f;
    unsigned u = v.u;
    return (unsigned short)((u + 0x7fffu + ((u >> 16) & 1u)) >> 16);  // RNE
}
__device__ __forceinline__ unsigned pack2(float a, float b) {
    return (unsigned)f2bf(a) | ((unsigned)f2bf(b) << 16);
}
// NOTE (R6 lesson): inline-asm v_cvt_pk_bf16_f32 regressed absmax 0.031->0.334
// (rounding semantics differ from RNE f2bf). Keep the bit-twiddle.
// fp16 pair pack for L'/R' LDS storage (fp16: rel err 2^-11, negligible here)
__device__ __forceinline__ unsigned packh2(float a, float b) {
    union { _Float16 h[2]; unsigned u; } v;
    v.h[0] = (_Float16)a; v.h[1] = (_Float16)b;
    return v.u;
}
// v_dot2_f32_f16: 2 fp16 products accumulated into fp32
__device__ __forceinline__ float fdot2f(unsigned a, unsigned b, float c) {
#if __has_builtin(__builtin_amdgcn_fdot2)
    union { unsigned u; half2_ h; } ua, ub; ua.u = a; ub.u = b;
    return __builtin_amdgcn_fdot2(ua.h, ub.h, c, false);
#else
    union { unsigned u; _Float16 h[2]; } ua, ub; ua.u = a; ub.u = b;
    return c + (float)ua.h[0] * (float)ub.h[0] + (float)ua.h[1] * (float)ub.h[1];
#endif
}

// ws (bf16 elements): [0,24576) conv A-frags  W2c[t][q][w][lane][j]
//                     [24576,32768) linear A-frags Wf[mat][l0s][mt][lane][j]
__global__ void prep_w(const float* __restrict__ Wconv,
                       const float* __restrict__ Wl,
                       const float* __restrict__ Wr,
                       unsigned short* __restrict__ W2) {
    int o = blockIdx.x * 256 + threadIdx.x;          // 0..32767
    if (o < 24576) {
        int j = o & 7, lane = (o >> 3) & 63, w = (o >> 9) & 3, q = (o >> 11) & 3, t = o >> 13;
        int m = lane & 15, quad = lane >> 4;
        int k = 16 * w + m, c = 32 * q + 8 * quad + j;
        W2[o] = f2bf(Wconv[(k * 128 + c) * 3 + t]);
    } else {
        int o2 = o - 24576;
        int j = o2 & 7, lane = (o2 >> 3) & 63, mt = (o2 >> 9) & 3,
            l0s = (o2 >> 11) & 1, mat = (o2 >> 12) & 1;
        int m = lane & 15, quad = lane >> 4;
        int k = 16 * mt + m, l = 32 * l0s + quad * 8 + j;
        const float* src = mat ? Wr : Wl;
        W2[o] = f2bf(src[k * 64 + l]);
    }
}

// ---- unified correlation pass (ONE code path shared by all 4 waves; I$-small) ----
// Cross-correlation view: corr[63-s] = F(L,R,s) = sum_j L[j]*R[j+s]  (s in [0,63])
//                         corr[64+s'] = F(R,L,s'+1)                  (s' in [0,63])
// Wave w runs 4 passes; each pass computes 8 shifts (one 8-channel corrT group):
//   A0: F(L,R, 8w+u)       -> group 7-w   A1: F(L,R, 56-8w+u) -> group w
//   B0: F(R,L, 8w+1+u)     -> group 8+w   B1: F(R,L, 57-8w+u) -> group 15-w
// shift s = 2q + ODD + u, with q = 4w or 28-4w (q%4==0 so the LDS pair-swizzle
// bit for Y pair t2+q equals ((t2>>1)&1), a compile-time immediate).
// P[t2] = Y-pair(t2+q); when t2+q>=32 the ADDRESS is clamped to row q (in-bounds,
// wave-uniform cselect) and the VALUE zeroed (exact Y zero-padding).
// AL[t2] = misaligned pair (hi of P[t2], lo of P[t2+1]).
// Swizzle is lane ^ (bit<<4) (XOR, not add).
template<int NJ2, bool ODD, bool REV>
__device__ __forceinline__ void corr_pass(const unsigned* __restrict__ X,
                                          const unsigned* __restrict__ Y,
                                          int q, int climit, int G,
                                          int lane, bool colvalid,
                                          unsigned short* __restrict__ corrT) {
    constexpr int SAFE = (NJ2 == 32) ? 20 : 4;   // t2 below SAFE can never have t2+q>=32
    unsigned P[NJ2 + 1];
    const unsigned* Yq = Y + q * 64;
#pragma unroll
    for (int t2 = 0; t2 <= NJ2; ++t2) {
        int off = t2 * 64;
        bool oob = false;
        if (t2 >= SAFE) { oob = (t2 + q >= 32); if (oob) off = 0; }   // uniform clamp
        unsigned v = Yq[off + (lane ^ ((((t2 >> 1) & 1)) << 4))];
        P[t2] = oob ? 0u : v;
    }
    unsigned AL[NJ2];
#pragma unroll
    for (int t2 = 0; t2 < NJ2; ++t2)
        AL[t2] = (P[t2] >> 16) | (P[t2 + 1] << 16);   // v_alignbit

    float acc[8];
#pragma unroll
    for (int u = 0; u < 8; ++u) acc[u] = 0.0f;

#pragma unroll
    for (int c = 0; c < NJ2 / 4; ++c) {
        if (c < climit) {            // uniform early-skip; skipped chunks are all-zero terms
            unsigned xp[4];
#pragma unroll
            for (int jj = 0; jj < 4; ++jj) {
                int j2 = 4 * c + jj;
                xp[jj] = X[j2 * 64 + (lane ^ ((((j2 >> 1) & 1)) << 4))];
            }
#pragma unroll
            for (int jj = 0; jj < 4; ++jj) {
                int j2 = 4 * c + jj;
#pragma unroll
                for (int u = 0; u < 8; ++u) {
                    if (j2 < NJ2 - (u >> 1)) {
                        unsigned yv;
                        if (!ODD) yv = (u & 1) ? AL[j2 + (u >> 1)] : P[j2 + (u >> 1)];
                        else      yv = (u & 1) ? P[j2 + (u >> 1) + 1] : AL[j2 + (u >> 1)];
                        acc[u] = fdot2f(xp[jj], yv, acc[u]);
                    }
                }
            }
        }
    }
    // pack + swizzled b128 store of one 8-channel group (RNE f2bf — see R6 note)
    short8 v;
#pragma unroll
    for (int u = 0; u < 8; ++u) {
        int jg = REV ? (7 - u) : u;
        v[jg] = colvalid ? (short)f2bf(acc[u]) : (short)0;   // colvalid = conv zero-pad at d=-1/D
    }
    int phys = G ^ (lane & 7);
    *(short8*)&corrT[lane * 128 + phys * 8] = v;
}

template<bool PRE>
__global__ __launch_bounds__(256, 3)
void fused_cc_kernel(const float* __restrict__ left,
                     const float* __restrict__ right,
                     const float* __restrict__ Wl,
                     const float* __restrict__ bl,
                     const float* __restrict__ Wr,
                     const float* __restrict__ br,
                     const float* __restrict__ Wconv,
                     const unsigned short* __restrict__ W2,
                     float* __restrict__ out) {
    // 32768 B exactly -> 5 blocks/CU (160 KiB / 32 KiB).
    // shm[0..4095]    : staging xL[2048]+xR[2048]  |  later corrT bf16 [64][128] swizzled
    // shm[4096..6143] : Lh fp16-pairs [32 lpair][64 d] (pair-parity swizzle)
    // shm[6144..8191] : Rh fp16-pairs
    // corr_pass OOB rows are address-clamped (no pad needed); corrT halo rows 64/65
    // read garbage from the Lh region -> feeds only discarded output cols 62/63.
    __shared__ unsigned shm[8192];
    unsigned* xL = shm;
    unsigned* xR = shm + 2048;
    unsigned* Lh = shm + 4096;
    unsigned* Rh = shm + 6144;
    unsigned short* corrT = (unsigned short*)shm;

    const int tid  = threadIdx.x;
    const int lane = tid & 63;
    const int w    = __builtin_amdgcn_readfirstlane(tid >> 6);
    const int kw   = 16 * w;
    const int m16  = lane & 15;
    const int quad = lane >> 4;

    const int b       = blockIdx.y;
    const int d_start = blockIdx.x * TD;
    const int ncols   = min(TD, DD - d_start);

    const int  g        = d_start - 1 + lane;      // global d for local column = lane
    const bool colvalid = (g >= 0) && (g < DD);

    const float* lb = left  + (size_t)b * 64 * DD;
    const float* rb = right + (size_t)b * 64 * DD;

    // ---- hoisted: linear A-frags + biases (global loads overlap P1's input loads)
    short8 afL[2], afR[2];
    if (PRE) {
        const short8* Wf = (const short8*)(W2 + 24576);
        afL[0] = Wf[(0 * 4 + w) * 64 + lane];
        afL[1] = Wf[(1 * 4 + w) * 64 + lane];
        afR[0] = Wf[(2 * 4 + w) * 64 + lane];
        afR[1] = Wf[(3 * 4 + w) * 64 + lane];
    } else {
#pragma unroll
        for (int l0s = 0; l0s < 2; ++l0s) {
            const float* pL = Wl + (kw + m16) * 64 + 32 * l0s + quad * 8;
            const float* pR = Wr + (kw + m16) * 64 + 32 * l0s + quad * 8;
#pragma unroll
            for (int j = 0; j < 8; ++j) {
                afL[l0s][j] = (short)f2bf(pL[j]);
                afR[l0s][j] = (short)f2bf(pR[j]);
            }
        }
    }
    float blv[4], brv[4];
#pragma unroll
    for (int r = 0; r < 4; ++r) {
        int krow = kw + quad * 4 + r;
        blv[r] = bl[krow]; brv[r] = br[krow];
    }

    // ---- P1: stage both inputs as bf16 l-pairs (coalesced global; swizzled LDS dest)
#pragma unroll
    for (int i = 0; i < 8; ++i) {
        int p = 8 * w + i, l = 2 * p;
        float a0 = colvalid ? lb[l * DD + g] : 0.0f;
        float a1 = colvalid ? lb[(l + 1) * DD + g] : 0.0f;
        float c0 = colvalid ? rb[l * DD + g] : 0.0f;
        float c1 = colvalid ? rb[(l + 1) * DD + g] : 0.0f;
        int pc = lane ^ (((p >> 2) & 1) << 4);     // quad-parity swizzle (matches P2 reads)
        xL[p * 64 + pc] = pack2(a0, a1);
        xR[p * 64 + pc] = pack2(c0, c1);
    }
    __syncthreads();

    // ---- P2: both linears via MFMA (A = W frags, B = staged input), M=64,N=64,K=64
    float4_ accL[4], accR[4];
#pragma unroll
    for (int nt = 0; nt < 4; ++nt) { accL[nt] = (float4_){0,0,0,0}; accR[nt] = (float4_){0,0,0,0}; }
#pragma unroll
    for (int l0s = 0; l0s < 2; ++l0s)
#pragma unroll
        for (int nt = 0; nt < 4; ++nt) {
            union { unsigned u[4]; short8 s; } tL, tR;
#pragma unroll
            for (int jj = 0; jj < 4; ++jj) {
                int row = l0s * 16 + quad * 4 + jj;
                int col = (nt * 16 + m16) ^ (((row >> 2) & 1) << 4);
                int a = row * 64 + col;
                tL.u[jj] = xL[a];
                tR.u[jj] = xR[a];
            }
            accL[nt] = __builtin_amdgcn_mfma_f32_16x16x32_bf16(afL[l0s], tL.s, accL[nt], 0, 0, 0);
            accR[nt] = __builtin_amdgcn_mfma_f32_16x16x32_bf16(afR[l0s], tR.s, accR[nt], 0, 0, 0);
        }

    // bias + scatter C-layout -> Lh/Rh fp16 pairs [k2][d] (pair-parity swizzle, conflict-free)
#pragma unroll
    for (int nt = 0; nt < 4; ++nt) {
        int col = nt * 16 + m16;
        int k2  = 8 * w + 2 * quad;               // pair rows (kw+4q)/2 and +1
        int c0 = col ^ ((quad & 1) << 4);         // ((k2>>1)&1) == quad&1 for both pairs
        Lh[k2 * 64 + c0]       = packh2(accL[nt][0] + blv[0], accL[nt][1] + blv[1]);
        Lh[(k2 + 1) * 64 + c0] = packh2(accL[nt][2] + blv[2], accL[nt][3] + blv[3]);
        Rh[k2 * 64 + c0]       = packh2(accR[nt][0] + brv[0], accR[nt][1] + brv[1]);
        Rh[(k2 + 1) * 64 + c0] = packh2(accR[nt][2] + brv[2], accR[nt][3] + brv[3]);
    }
    __syncthreads();   // staging reads done everywhere; Lh/Rh visible

    // ---- P3: unified balanced corr (shared code, dot2) -> corrT (bf16, swizzled)
    corr_pass<32, false, true >(Lh, Rh, 4 * w,      8 - w, 7 - w,  lane, colvalid, corrT);
    corr_pass<16, false, true >(Lh, Rh, 28 - 4 * w, w + 1, w,      lane, colvalid, corrT);
    corr_pass<32, true,  false>(Rh, Lh, 4 * w,      8 - w, 8 + w,  lane, colvalid, corrT);
    corr_pass<16, true,  false>(Rh, Lh, 28 - 4 * w, w + 1, 15 - w, lane, colvalid, corrT);

    // conv A-frag loads: latency hides under last stores + barrier
    short8 af[12];
#pragma unroll
    for (int t = 0; t < 3; ++t)
#pragma unroll
        for (int qi = 0; qi < 4; ++qi) {
            if (PRE) {
                af[t * 4 + qi] = ((const short8*)W2)[((t * 4 + qi) * 4 + w) * 64 + lane];
            } else {
                const float* p = Wconv + ((kw + m16) * 128 + 32 * qi + 8 * quad) * 3 + t;
#pragma unroll
                for (int j = 0; j < 8; ++j) af[t * 4 + qi][j] = (short)f2bf(p[3 * j]);
            }
        }
    __syncthreads();

    // ---- P4: conv via MFMA over all 128 c (3 taps x 4 c-groups x 4 n-tiles)
    float4_ yacc[4];
#pragma unroll
    for (int nt = 0; nt < 4; ++nt) yacc[nt] = (float4_){0,0,0,0};
#pragma unroll
    for (int t = 0; t < 3; ++t)
#pragma unroll
        for (int qi = 0; qi < 4; ++qi)
#pragma unroll
            for (int nt = 0; nt < 4; ++nt) {
                int row  = nt * 16 + m16 + t;                 // 0..65 (64,65 -> discarded cols)
                int phys = (4 * qi + quad) ^ (row & 7);
                short8 bf = *(const short8*)&corrT[row * 128 + phys * 8];
                yacc[nt] = __builtin_amdgcn_mfma_f32_16x16x32_bf16(af[t * 4 + qi], bf,
                                                                   yacc[nt], 0, 0, 0);
            }

    // ---- P5: store y[b,k,d]  (D layout: col=lane&15 -> d, row=quad*4+r -> k)
#pragma unroll
    for (int nt = 0; nt < 4; ++nt) {
        const int dd = nt * 16 + m16;
        if (dd < ncols) {
#pragma unroll
            for (int r = 0; r < 4; ++r) {
                int k = kw + 4 * quad + r;
                out[((size_t)b * 64 + k) * DD + d_start + dd] = yacc[nt][r];
            }
        }
    }
}

extern "C" void kernel_launch(void* const* d_in, const int* in_sizes, int n_in,
                              void* d_out, int out_size, void* d_ws, size_t ws_size,
                              hipStream_t stream) {
    const float* left  = (const float*)d_in[0];
    const float* right = (const float*)d_in[1];
    const float* Wl    = (const float*)d_in[2];
    const float* bl    = (const float*)d_in[3];
    const float* Wr    = (const float*)d_in[4];
    const float* br    = (const float*)d_in[5];
    const float* Wconv = (const float*)d_in[6];
    float* out = (float*)d_out;

    dim3 grid(NTILE, BB);
    if (ws_size >= 32768 * sizeof(unsigned short)) {
        unsigned short* W2 = (unsigned short*)d_ws;
        prep_w<<<128, 256, 0, stream>>>(Wconv, Wl, Wr, W2);
        fused_cc_kernel<true><<<grid, dim3(256), 0, stream>>>(left, right, Wl, bl, Wr, br,
                                                              Wconv, W2, out);
    } else {
        fused_cc_kernel<false><<<grid, dim3(256), 0, stream>>>(left, right, Wl, bl, Wr, br,
                                                               Wconv, nullptr, out);
    }
}